// Round 1
// 281.159 us; speedup vs baseline: 1.2308x; 1.2308x over previous
//
#include <hip/hip_runtime.h>
#include <stdint.h>

// Problem constants (fp32 inputs/outputs — confirmed by round-4 pass)
#define Bb 2
#define Ss 1024
#define Dd 512
#define Hh 8
#define HD 4096   // Hh*Dd
#define Mm 2048   // Bb*Ss

typedef _Float16 f16x8 __attribute__((ext_vector_type(8)));
typedef _Float16 f16x4 __attribute__((ext_vector_type(4)));
typedef float    f32x4 __attribute__((ext_vector_type(4)));

// async global->LDS, 16B per lane. dest must be linear: base + lane*16.
#define GLOAD16(g, l)                                                          \
    __builtin_amdgcn_global_load_lds(                                          \
        (const __attribute__((address_space(1))) void*)(g),                    \
        (__attribute__((address_space(3))) void*)(l), 16, 0, 0)

// ---------------------------------------------------------------------------
// cvt_f16: fp32 -> f16 elementwise (x/y staging). n multiple of 1024.
// ---------------------------------------------------------------------------
__global__ __launch_bounds__(256) void cvt_f16(
    const float* __restrict__ in, _Float16* __restrict__ out, int n)
{
    int i = (blockIdx.x * 256 + threadIdx.x) * 4;
    if (i < n) {
        float4 u = *(const float4*)(in + i);
        f16x4 o;
        o[0] = (_Float16)u.x; o[1] = (_Float16)u.y;
        o[2] = (_Float16)u.z; o[3] = (_Float16)u.w;
        *(f16x4*)(out + i) = o;
    }
}

// ---------------------------------------------------------------------------
// cvt_w_pk: W fp32 [512][ld], cols [col0, col0+NC) -> f16 k-pack8:
//   out[((k/8)*NC + n)*8 + (k%8)]
// ---------------------------------------------------------------------------
__global__ __launch_bounds__(256) void cvt_w_pk(
    const float* __restrict__ W, int ld, int col0,
    _Float16* __restrict__ out, int NC)
{
    const int n  = blockIdx.x * 256 + threadIdx.x;
    const int k0 = blockIdx.y * 8;
    f16x8 o;
#pragma unroll
    for (int j = 0; j < 8; j++)
        o[j] = (_Float16)W[(size_t)(k0 + j) * ld + col0 + n];
    *(f16x8*)(out + ((size_t)(k0 >> 3) * NC + n) * 8) = o;
}

// ---------------------------------------------------------------------------
// proj_f16: C[2048, NC] = A[2048,512](f16 row-major) @ Wpk(k-pack8) + bias.
// 128x128 tile, 4 waves, 64x64/wave. LDS double-buffered 2-phase via
// global_load_lds (16B). A tile: [row][chunk] with chunk^=(row>>2)&3 swizzle
// (pre-swizzled global source). B tile: [chunk][row] (pack8-native, coalesced).
// ---------------------------------------------------------------------------
__global__ __launch_bounds__(256) void proj_f16(
    const _Float16* __restrict__ A, const _Float16* __restrict__ Wpk,
    const float* __restrict__ bias, int bias0,
    _Float16* __restrict__ C, int NC, int packC)
{
    __shared__ _Float16 lsA[2][4096];
    __shared__ _Float16 lsB[2][4096];
    const int t = threadIdx.x;
    const int lane = t & 63, wave = t >> 6;
    const int quad = lane >> 4, l15 = lane & 15;
    const int m0b = blockIdx.y * 128, n0b = blockIdx.x * 128;
    const int aw = (wave >> 1) * 64, bw = (wave & 1) * 64;
    const int qx = (quad ^ ((l15 >> 2) & 3)) * 8;   // swizzled chunk for A reads

    // A staging: thread t -> row t>>2 (+64 on 2nd call), src chunk swizzled
    const _Float16* ag = A + (size_t)(m0b + (t >> 2)) * Dd
                           + ((t & 3) ^ ((t >> 4) & 3)) * 8;
    // B staging: thread t -> k-chunk t>>7 (+2 on 2nd call), col t&127
    const _Float16* bg = Wpk + ((size_t)(t >> 7) * NC + n0b + (t & 127)) * 8;
    const size_t arj = (size_t)64 * Dd;   // +64 rows
    const size_t bcs = (size_t)NC * 8;    // one k-chunk (8 k)

    f32x4 acc[4][4] = {};
    GLOAD16(ag,           &lsA[0][t * 8]);
    GLOAD16(ag + arj,     &lsA[0][t * 8 + 2048]);
    GLOAD16(bg,           &lsB[0][t * 8]);
    GLOAD16(bg + 2 * bcs, &lsB[0][t * 8 + 2048]);
    __syncthreads();
    int cur = 0;
    for (int kb = 0; kb < Dd; kb += 32) {
        if (kb + 32 < Dd) {
            const int nb = cur ^ 1;
            GLOAD16(ag + kb + 32,       &lsA[nb][t * 8]);
            GLOAD16(ag + arj + kb + 32, &lsA[nb][t * 8 + 2048]);
            GLOAD16(bg + (size_t)((kb >> 3) + 4) * bcs, &lsB[nb][t * 8]);
            GLOAD16(bg + (size_t)((kb >> 3) + 6) * bcs, &lsB[nb][t * 8 + 2048]);
        }
        f16x8 af[4], bf[4];
#pragma unroll
        for (int mi = 0; mi < 4; mi++)
            af[mi] = *(const f16x8*)&lsA[cur][(aw + mi * 16 + l15) * 32 + qx];
#pragma unroll
        for (int ni = 0; ni < 4; ni++)
            bf[ni] = *(const f16x8*)&lsB[cur][quad * 1024 + (bw + ni * 16 + l15) * 8];
#pragma unroll
        for (int mi = 0; mi < 4; mi++)
#pragma unroll
            for (int ni = 0; ni < 4; ni++)
                acc[mi][ni] = __builtin_amdgcn_mfma_f32_16x16x32_f16(af[mi], bf[ni], acc[mi][ni], 0, 0, 0);
        __syncthreads();
        cur ^= 1;
    }

#pragma unroll
    for (int mi = 0; mi < 4; mi++) {
#pragma unroll
        for (int ni = 0; ni < 4; ni++) {
            const int col = n0b + bw + ni * 16 + l15;
            const float bv = bias ? bias[bias0 + col] : 0.0f;
#pragma unroll
            for (int r = 0; r < 4; r++) {
                const int row = m0b + aw + mi * 16 + quad * 4 + r;
                const _Float16 val = (_Float16)(acc[mi][ni][r] + bv);
                if (packC)
                    C[((size_t)(row >> 3) * NC + col) * 8 + (row & 7)] = val;
                else
                    C[(size_t)row * NC + col] = val;
            }
        }
    }
}

// ---------------------------------------------------------------------------
// energy_f16: E[s,t] = sum_c q[s,c]*k[t,c]; masked col -> -30000.
// Both operands row-major -> both staged [row][chunk-swizzled] in LDS,
// double-buffered 2-phase.
// ---------------------------------------------------------------------------
__global__ __launch_bounds__(256) void energy_f16(
    const _Float16* __restrict__ Q, const _Float16* __restrict__ Kb,
    const int* __restrict__ mask, _Float16* __restrict__ E, int NC)
{
    __shared__ _Float16 lsA[2][4096];
    __shared__ _Float16 lsB[2][4096];
    const int zl = blockIdx.z;
    const int b = zl & 1, hloc = zl >> 1;
    const _Float16* qz = Q + (size_t)b * Ss * NC + hloc * Dd;
    const _Float16* kz = Kb + (size_t)b * Ss * NC + hloc * Dd;
    _Float16* Ez = E + (size_t)zl * Ss * Ss;

    const int t = threadIdx.x;
    const int lane = t & 63, wave = t >> 6;
    const int quad = lane >> 4, l15 = lane & 15;
    const int m0b = blockIdx.y * 128, n0b = blockIdx.x * 128;
    const int aw = (wave >> 1) * 64, bw = (wave & 1) * 64;
    const int qx = (quad ^ ((l15 >> 2) & 3)) * 8;

    const int sc = ((t & 3) ^ ((t >> 4) & 3)) * 8;   // pre-swizzled src chunk
    const _Float16* ag = qz + (size_t)(m0b + (t >> 2)) * NC + sc;
    const _Float16* bg = kz + (size_t)(n0b + (t >> 2)) * NC + sc;
    const size_t rj = (size_t)64 * NC;

    f32x4 acc[4][4] = {};
    GLOAD16(ag,      &lsA[0][t * 8]);
    GLOAD16(ag + rj, &lsA[0][t * 8 + 2048]);
    GLOAD16(bg,      &lsB[0][t * 8]);
    GLOAD16(bg + rj, &lsB[0][t * 8 + 2048]);
    __syncthreads();
    int cur = 0;
    for (int kb = 0; kb < Dd; kb += 32) {
        if (kb + 32 < Dd) {
            const int nb = cur ^ 1;
            GLOAD16(ag + kb + 32,      &lsA[nb][t * 8]);
            GLOAD16(ag + rj + kb + 32, &lsA[nb][t * 8 + 2048]);
            GLOAD16(bg + kb + 32,      &lsB[nb][t * 8]);
            GLOAD16(bg + rj + kb + 32, &lsB[nb][t * 8 + 2048]);
        }
        f16x8 af[4], bf[4];
#pragma unroll
        for (int mi = 0; mi < 4; mi++)
            af[mi] = *(const f16x8*)&lsA[cur][(aw + mi * 16 + l15) * 32 + qx];
#pragma unroll
        for (int ni = 0; ni < 4; ni++)
            bf[ni] = *(const f16x8*)&lsB[cur][(bw + ni * 16 + l15) * 32 + qx];
#pragma unroll
        for (int mi = 0; mi < 4; mi++)
#pragma unroll
            for (int ni = 0; ni < 4; ni++)
                acc[mi][ni] = __builtin_amdgcn_mfma_f32_16x16x32_f16(af[mi], bf[ni], acc[mi][ni], 0, 0, 0);
        __syncthreads();
        cur ^= 1;
    }

#pragma unroll
    for (int ni = 0; ni < 4; ni++) {
        const int col = n0b + bw + ni * 16 + l15;
        const int keep = mask[col];
#pragma unroll
        for (int mi = 0; mi < 4; mi++) {
#pragma unroll
            for (int r = 0; r < 4; r++) {
                const int row = m0b + aw + mi * 16 + quad * 4 + r;
                Ez[(size_t)row * Ss + col] = keep ? (_Float16)acc[mi][ni][r]
                                                  : (_Float16)(-30000.0f);
            }
        }
    }
}

// ---------------------------------------------------------------------------
// softmax_pk: one block = 8 consecutive global rows x 1024 t. Output k-pack8.
// ---------------------------------------------------------------------------
__global__ __launch_bounds__(256) void softmax_pk(
    const _Float16* __restrict__ E, _Float16* __restrict__ At)
{
    const int rb = blockIdx.x;                       // row-group (8 rows)
    const _Float16* e0 = E + (size_t)rb * 8 * Ss;
    const int tid = threadIdx.x;
    const int wave = tid >> 6, lane = tid & 63;
    const int t0 = tid * 4;

    float v[8][4];
#pragma unroll
    for (int r = 0; r < 8; r++) {
        f16x4 u = *(const f16x4*)(e0 + (size_t)r * Ss + t0);
#pragma unroll
        for (int j = 0; j < 4; j++) v[r][j] = (float)u[j];
    }

    __shared__ float red[4][8];
    float mx[8];
#pragma unroll
    for (int r = 0; r < 8; r++) {
        float lm = fmaxf(fmaxf(v[r][0], v[r][1]), fmaxf(v[r][2], v[r][3]));
#pragma unroll
        for (int off = 1; off < 64; off <<= 1) lm = fmaxf(lm, __shfl_xor(lm, off));
        mx[r] = lm;
    }
    if (lane == 0) {
#pragma unroll
        for (int r = 0; r < 8; r++) red[wave][r] = mx[r];
    }
    __syncthreads();
#pragma unroll
    for (int r = 0; r < 8; r++)
        mx[r] = fmaxf(fmaxf(red[0][r], red[1][r]), fmaxf(red[2][r], red[3][r]));
    __syncthreads();

    float inv[8];
#pragma unroll
    for (int r = 0; r < 8; r++) {
        v[r][0] = __expf(v[r][0] - mx[r]); v[r][1] = __expf(v[r][1] - mx[r]);
        v[r][2] = __expf(v[r][2] - mx[r]); v[r][3] = __expf(v[r][3] - mx[r]);
        float ls = (v[r][0] + v[r][1]) + (v[r][2] + v[r][3]);
#pragma unroll
        for (int off = 1; off < 64; off <<= 1) ls += __shfl_xor(ls, off);
        inv[r] = ls;
    }
    if (lane == 0) {
#pragma unroll
        for (int r = 0; r < 8; r++) red[wave][r] = inv[r];
    }
    __syncthreads();
#pragma unroll
    for (int r = 0; r < 8; r++) {
        const float s = (red[0][r] + red[1][r]) + (red[2][r] + red[3][r]);
        inv[r] = (s > 0.0f) ? (1.0f / s) : 0.0f;
    }

    _Float16* ob = At + (size_t)rb * Ss * 8;
#pragma unroll
    for (int j = 0; j < 4; j++) {
        f16x8 o;
#pragma unroll
        for (int r = 0; r < 8; r++) o[r] = (_Float16)(v[r][j] * inv[r]);
        *(f16x8*)(ob + (size_t)(t0 + j) * 8) = o;
    }
}

// ---------------------------------------------------------------------------
// pv_f16: out[t,c] = sum_s P[s,t]*v[s,c]. Both operands k-pack8 -> both
// staged [chunk][row] in LDS (coalesced, conflict-light). 2-phase dbuf.
// Epilogue (g*acc + xp)/(g+1) -> fp32 d_out.
// ---------------------------------------------------------------------------
__global__ __launch_bounds__(256) void pv_f16(
    const _Float16* __restrict__ At, const _Float16* __restrict__ Vpk,
    const _Float16* __restrict__ Xp, const float* __restrict__ G,
    float* __restrict__ Out, int h0, int NC)
{
    __shared__ _Float16 lsA[2][4096];
    __shared__ _Float16 lsB[2][4096];
    const int zl = blockIdx.z;
    const int b = zl & 1, hloc = zl >> 1;
    const int h = h0 + hloc;
    const _Float16* az = At + (size_t)zl * Ss * Ss;   // k-pack8 per z-slice

    const int t = threadIdx.x;
    const int lane = t & 63, wave = t >> 6;
    const int quad = lane >> 4, l15 = lane & 15;
    const int m0b = blockIdx.y * 128, n0b = blockIdx.x * 128;
    const int aw = (wave >> 1) * 64, bw = (wave & 1) * 64;

    const _Float16* ag = az + ((size_t)(t >> 7) * Ss + m0b + (t & 127)) * 8;
    const _Float16* bg = Vpk + (((size_t)((b * Ss) >> 3) + (t >> 7)) * NC
                                + hloc * Dd + n0b + (t & 127)) * 8;
    const size_t acs = (size_t)Ss * 8;
    const size_t bcs = (size_t)NC * 8;

    f32x4 acc[4][4] = {};
    GLOAD16(ag,           &lsA[0][t * 8]);
    GLOAD16(ag + 2 * acs, &lsA[0][t * 8 + 2048]);
    GLOAD16(bg,           &lsB[0][t * 8]);
    GLOAD16(bg + 2 * bcs, &lsB[0][t * 8 + 2048]);
    __syncthreads();
    int cur = 0;
    for (int kb = 0; kb < Ss; kb += 32) {
        if (kb + 32 < Ss) {
            const int nb = cur ^ 1;
            GLOAD16(ag + ((size_t)(kb >> 3) + 4) * acs, &lsA[nb][t * 8]);
            GLOAD16(ag + ((size_t)(kb >> 3) + 6) * acs, &lsA[nb][t * 8 + 2048]);
            GLOAD16(bg + ((size_t)(kb >> 3) + 4) * bcs, &lsB[nb][t * 8]);
            GLOAD16(bg + ((size_t)(kb >> 3) + 6) * bcs, &lsB[nb][t * 8 + 2048]);
        }
        f16x8 af[4], bf[4];
#pragma unroll
        for (int mi = 0; mi < 4; mi++)
            af[mi] = *(const f16x8*)&lsA[cur][quad * 1024 + (aw + mi * 16 + l15) * 8];
#pragma unroll
        for (int ni = 0; ni < 4; ni++)
            bf[ni] = *(const f16x8*)&lsB[cur][quad * 1024 + (bw + ni * 16 + l15) * 8];
#pragma unroll
        for (int mi = 0; mi < 4; mi++)
#pragma unroll
            for (int ni = 0; ni < 4; ni++)
                acc[mi][ni] = __builtin_amdgcn_mfma_f32_16x16x32_f16(af[mi], bf[ni], acc[mi][ni], 0, 0, 0);
        __syncthreads();
        cur ^= 1;
    }

    const float g = G[h];
    const float inv = 1.0f / (g + 1.0f);
#pragma unroll
    for (int mi = 0; mi < 4; mi++) {
#pragma unroll
        for (int ni = 0; ni < 4; ni++) {
            const int c = n0b + bw + ni * 16 + l15;
#pragma unroll
            for (int r = 0; r < 4; r++) {
                const int tt = m0b + aw + mi * 16 + quad * 4 + r;
                const float xpv = (float)Xp[(size_t)(b * Ss + tt) * Dd + c];
                Out[(size_t)((b * Hh + h) * Ss + tt) * Dd + c] =
                    (g * acc[mi][ni][r] + xpv) * inv;
            }
        }
    }
}

// ---------------------------------------------------------------------------
// Workspace (HG=4, guaranteed fit in 62 MiB; HG=8 if ws >= 128 MiB):
//   Wbuf  512*NC f16          (k-pack8 staging, reused per weight)
//   q, k  [2048][NC] f16 row-major
//   v     [2048][NC] f16 k-pack8 over rows
//   xp    [2048][512] f16
//   en    [2*HG][1024][1024] f16       (xf/yf staging aliases its head)
//   at    [2*HG] k-pack8 f16
// ---------------------------------------------------------------------------
extern "C" void kernel_launch(void* const* d_in, const int* in_sizes, int n_in,
                              void* d_out, int out_size, void* d_ws, size_t ws_size,
                              hipStream_t stream) {
    const float* x    = (const float*)d_in[0];
    const float* y    = (const float*)d_in[1];
    const float* Wq   = (const float*)d_in[2];
    const float* bq   = (const float*)d_in[3];
    const float* Wk   = (const float*)d_in[4];
    const float* bk   = (const float*)d_in[5];
    const float* Wv   = (const float*)d_in[6];
    const float* bv   = (const float*)d_in[7];
    const float* Wp   = (const float*)d_in[8];
    const float* gm   = (const float*)d_in[9];
    const int*   mask = (const int*)d_in[10];

    const int HG = (ws_size >= (size_t)134217728) ? 8 : 4;   // heads per group
    const int NC = HG * Dd;
    const int NZ = 2 * HG;                                    // z per group

    char* ws = (char*)d_ws;
    size_t off = 0;
    _Float16* Wbuf = (_Float16*)(ws + off); off += (size_t)512 * NC * 2;
    _Float16* qb   = (_Float16*)(ws + off); off += (size_t)Mm * NC * 2;
    _Float16* kb   = (_Float16*)(ws + off); off += (size_t)Mm * NC * 2;
    _Float16* vb   = (_Float16*)(ws + off); off += (size_t)Mm * NC * 2;
    _Float16* xp   = (_Float16*)(ws + off); off += (size_t)Mm * Dd * 2;
    _Float16* en   = (_Float16*)(ws + off); off += (size_t)NZ * Ss * Ss * 2;
    _Float16* at   = (_Float16*)(ws + off);
    _Float16* xf   = en;                      // staging inside en region
    _Float16* yf   = en + (size_t)Mm * 512;   // (4 MiB << en size)

    dim3 blk(256);
    const int NXY = Mm * 512;

    // xp = x @ Wp (no bias)
    cvt_f16<<<dim3(NXY / 1024), blk, 0, stream>>>(x, xf, NXY);
    cvt_w_pk<<<dim3(2, 64), blk, 0, stream>>>(Wp, Dd, 0, Wbuf, Dd);
    proj_f16<<<dim3(4, 16), blk, 0, stream>>>(xf, Wbuf, nullptr, 0, xp, Dd, 0);

    for (int h0 = 0; h0 < Hh; h0 += HG) {
        // re-stage x/y (en region was clobbered by previous group's energy)
        cvt_f16<<<dim3(NXY / 1024), blk, 0, stream>>>(x, xf, NXY);
        cvt_f16<<<dim3(NXY / 1024), blk, 0, stream>>>(y, yf, NXY);

        cvt_w_pk<<<dim3(NC / 256, 64), blk, 0, stream>>>(Wq, HD, h0 * Dd, Wbuf, NC);
        proj_f16<<<dim3(NC / 128, 16), blk, 0, stream>>>(xf, Wbuf, bq, h0 * Dd, qb, NC, 0);
        cvt_w_pk<<<dim3(NC / 256, 64), blk, 0, stream>>>(Wk, HD, h0 * Dd, Wbuf, NC);
        proj_f16<<<dim3(NC / 128, 16), blk, 0, stream>>>(yf, Wbuf, bk, h0 * Dd, kb, NC, 0);
        cvt_w_pk<<<dim3(NC / 256, 64), blk, 0, stream>>>(Wv, HD, h0 * Dd, Wbuf, NC);
        proj_f16<<<dim3(NC / 128, 16), blk, 0, stream>>>(yf, Wbuf, bv, h0 * Dd, vb, NC, 1);

        energy_f16<<<dim3(8, 8, NZ), blk, 0, stream>>>(qb, kb, mask, en, NC);
        softmax_pk<<<dim3(NZ * Ss / 8), blk, 0, stream>>>(en, at);
        pv_f16<<<dim3(4, 8, NZ), blk, 0, stream>>>(at, vb, xp, gm, (float*)d_out, h0, NC);
    }
}

// Round 2
// 266.744 us; speedup vs baseline: 1.2973x; 1.0540x over previous
//
#include <hip/hip_runtime.h>
#include <stdint.h>

// Problem constants (fp32 inputs/outputs — confirmed by round-4 pass)
#define Bb 2
#define Ss 1024
#define Dd 512
#define Hh 8
#define HD 4096   // Hh*Dd
#define Mm 2048   // Bb*Ss

typedef _Float16 f16x8 __attribute__((ext_vector_type(8)));
typedef _Float16 f16x4 __attribute__((ext_vector_type(4)));
typedef float    f32x4 __attribute__((ext_vector_type(4)));

// async global->LDS, 16B per lane. dest must be linear: base + lane*16.
#define GLOAD16(g, l)                                                          \
    __builtin_amdgcn_global_load_lds(                                          \
        (const __attribute__((address_space(1))) void*)(g),                    \
        (__attribute__((address_space(3))) void*)(l), 16, 0, 0)

// ---------------------------------------------------------------------------
// cvt_f16: fp32 -> f16 elementwise (x/y staging). n multiple of 1024.
// ---------------------------------------------------------------------------
__global__ __launch_bounds__(256) void cvt_f16(
    const float* __restrict__ in, _Float16* __restrict__ out, int n)
{
    int i = (blockIdx.x * 256 + threadIdx.x) * 4;
    if (i < n) {
        float4 u = *(const float4*)(in + i);
        f16x4 o;
        o[0] = (_Float16)u.x; o[1] = (_Float16)u.y;
        o[2] = (_Float16)u.z; o[3] = (_Float16)u.w;
        *(f16x4*)(out + i) = o;
    }
}

// ---------------------------------------------------------------------------
// cvt_w_pk: W fp32 [512][ld], cols [col0, col0+NC) -> f16 k-pack8:
//   out[((k/8)*NC + n)*8 + (k%8)]
// ---------------------------------------------------------------------------
__global__ __launch_bounds__(256) void cvt_w_pk(
    const float* __restrict__ W, int ld, int col0,
    _Float16* __restrict__ out, int NC)
{
    const int n  = blockIdx.x * 256 + threadIdx.x;
    const int k0 = blockIdx.y * 8;
    f16x8 o;
#pragma unroll
    for (int j = 0; j < 8; j++)
        o[j] = (_Float16)W[(size_t)(k0 + j) * ld + col0 + n];
    *(f16x8*)(out + ((size_t)(k0 >> 3) * NC + n) * 8) = o;
}

// ---------------------------------------------------------------------------
// proj_f16: C[2048, NC] = A[2048,512](f16 row-major) @ Wpk(k-pack8) + bias.
// 128x128 tile, 4 waves, 64x64/wave, 2-phase dbuf LDS via global_load_lds.
// packC=1 stores f16x4 (pack8 rows r=0..3 are contiguous halves).
// ---------------------------------------------------------------------------
__global__ __launch_bounds__(256) void proj_f16(
    const _Float16* __restrict__ A, const _Float16* __restrict__ Wpk,
    const float* __restrict__ bias, int bias0,
    _Float16* __restrict__ C, int NC, int packC)
{
    __shared__ _Float16 lsA[2][4096];
    __shared__ _Float16 lsB[2][4096];
    const int t = threadIdx.x;
    const int lane = t & 63, wave = t >> 6;
    const int quad = lane >> 4, l15 = lane & 15;
    const int m0b = blockIdx.y * 128, n0b = blockIdx.x * 128;
    const int aw = (wave >> 1) * 64, bw = (wave & 1) * 64;
    const int qx = (quad ^ ((l15 >> 2) & 3)) * 8;   // swizzled chunk for A reads

    const _Float16* ag = A + (size_t)(m0b + (t >> 2)) * Dd
                           + ((t & 3) ^ ((t >> 4) & 3)) * 8;
    const _Float16* bg = Wpk + ((size_t)(t >> 7) * NC + n0b + (t & 127)) * 8;
    const size_t arj = (size_t)64 * Dd;
    const size_t bcs = (size_t)NC * 8;

    f32x4 acc[4][4] = {};
    GLOAD16(ag,           &lsA[0][t * 8]);
    GLOAD16(ag + arj,     &lsA[0][t * 8 + 2048]);
    GLOAD16(bg,           &lsB[0][t * 8]);
    GLOAD16(bg + 2 * bcs, &lsB[0][t * 8 + 2048]);
    __syncthreads();
    int cur = 0;
    for (int kb = 0; kb < Dd; kb += 32) {
        if (kb + 32 < Dd) {
            const int nb = cur ^ 1;
            GLOAD16(ag + kb + 32,       &lsA[nb][t * 8]);
            GLOAD16(ag + arj + kb + 32, &lsA[nb][t * 8 + 2048]);
            GLOAD16(bg + (size_t)((kb >> 3) + 4) * bcs, &lsB[nb][t * 8]);
            GLOAD16(bg + (size_t)((kb >> 3) + 6) * bcs, &lsB[nb][t * 8 + 2048]);
        }
        f16x8 af[4], bf[4];
#pragma unroll
        for (int mi = 0; mi < 4; mi++)
            af[mi] = *(const f16x8*)&lsA[cur][(aw + mi * 16 + l15) * 32 + qx];
#pragma unroll
        for (int ni = 0; ni < 4; ni++)
            bf[ni] = *(const f16x8*)&lsB[cur][quad * 1024 + (bw + ni * 16 + l15) * 8];
#pragma unroll
        for (int mi = 0; mi < 4; mi++)
#pragma unroll
            for (int ni = 0; ni < 4; ni++)
                acc[mi][ni] = __builtin_amdgcn_mfma_f32_16x16x32_f16(af[mi], bf[ni], acc[mi][ni], 0, 0, 0);
        __syncthreads();
        cur ^= 1;
    }

#pragma unroll
    for (int mi = 0; mi < 4; mi++) {
        const int row0 = m0b + aw + mi * 16 + quad * 4;
#pragma unroll
        for (int ni = 0; ni < 4; ni++) {
            const int col = n0b + bw + ni * 16 + l15;
            const float bv = bias ? bias[bias0 + col] : 0.0f;
            if (packC) {
                f16x4 o;
#pragma unroll
                for (int r = 0; r < 4; r++) o[r] = (_Float16)(acc[mi][ni][r] + bv);
                *(f16x4*)(C + ((size_t)(row0 >> 3) * NC + col) * 8 + (row0 & 7)) = o;
            } else {
#pragma unroll
                for (int r = 0; r < 4; r++)
                    C[(size_t)(row0 + r) * NC + col] = (_Float16)(acc[mi][ni][r] + bv);
            }
        }
    }
}

// ---------------------------------------------------------------------------
// energy_f16: E[s,t] = sum_c q[s,c]*k[t,c]; masked t -> -30000.
// SWAPPED operands: A = K rows (M = t), B = Q rows (N = s) so each thread's
// 4 acc regs are consecutive t -> f16x4 E stores (8B) with int4 mask loads.
// Grid (NZ, 8, 8): z in blockIdx.x -> flat-id%8 = z -> one z-slice per XCD
// (Q+K+E working set ~4MB fits the XCD L2; redundant tile re-reads hit L2).
// ---------------------------------------------------------------------------
__global__ __launch_bounds__(256) void energy_f16(
    const _Float16* __restrict__ Q, const _Float16* __restrict__ Kb,
    const int* __restrict__ mask, _Float16* __restrict__ E, int NC)
{
    __shared__ _Float16 lsA[2][4096];   // K rows (t-block)
    __shared__ _Float16 lsB[2][4096];   // Q rows (s-block)
    const int zl = blockIdx.x;
    const int b = zl & 1, hloc = zl >> 1;
    const _Float16* qz = Q + (size_t)b * Ss * NC + hloc * Dd;
    const _Float16* kz = Kb + (size_t)b * Ss * NC + hloc * Dd;
    _Float16* Ez = E + (size_t)zl * Ss * Ss;

    const int t = threadIdx.x;
    const int lane = t & 63, wave = t >> 6;
    const int quad = lane >> 4, l15 = lane & 15;
    const int tb = blockIdx.y * 128;    // t-block (A / M side, from K)
    const int sb = blockIdx.z * 128;    // s-block (B / N side, from Q)
    const int aw = (wave >> 1) * 64, bw = (wave & 1) * 64;
    const int qx = (quad ^ ((l15 >> 2) & 3)) * 8;

    const int sc = ((t & 3) ^ ((t >> 4) & 3)) * 8;   // pre-swizzled src chunk
    const _Float16* ag = kz + (size_t)(tb + (t >> 2)) * NC + sc;
    const _Float16* bg = qz + (size_t)(sb + (t >> 2)) * NC + sc;
    const size_t rj = (size_t)64 * NC;

    f32x4 acc[4][4] = {};
    GLOAD16(ag,      &lsA[0][t * 8]);
    GLOAD16(ag + rj, &lsA[0][t * 8 + 2048]);
    GLOAD16(bg,      &lsB[0][t * 8]);
    GLOAD16(bg + rj, &lsB[0][t * 8 + 2048]);
    __syncthreads();
    int cur = 0;
    for (int kb = 0; kb < Dd; kb += 32) {
        if (kb + 32 < Dd) {
            const int nb = cur ^ 1;
            GLOAD16(ag + kb + 32,      &lsA[nb][t * 8]);
            GLOAD16(ag + rj + kb + 32, &lsA[nb][t * 8 + 2048]);
            GLOAD16(bg + kb + 32,      &lsB[nb][t * 8]);
            GLOAD16(bg + rj + kb + 32, &lsB[nb][t * 8 + 2048]);
        }
        f16x8 af[4], bf[4];
#pragma unroll
        for (int mi = 0; mi < 4; mi++)
            af[mi] = *(const f16x8*)&lsA[cur][(aw + mi * 16 + l15) * 32 + qx];
#pragma unroll
        for (int ni = 0; ni < 4; ni++)
            bf[ni] = *(const f16x8*)&lsB[cur][(bw + ni * 16 + l15) * 32 + qx];
#pragma unroll
        for (int mi = 0; mi < 4; mi++)
#pragma unroll
            for (int ni = 0; ni < 4; ni++)
                acc[mi][ni] = __builtin_amdgcn_mfma_f32_16x16x32_f16(af[mi], bf[ni], acc[mi][ni], 0, 0, 0);
        __syncthreads();
        cur ^= 1;
    }

#pragma unroll
    for (int mi = 0; mi < 4; mi++) {
        const int t0 = tb + aw + mi * 16 + quad * 4;
        const int4 mk = *(const int4*)(mask + t0);
#pragma unroll
        for (int ni = 0; ni < 4; ni++) {
            const int s = sb + bw + ni * 16 + l15;
            f16x4 o;
            o[0] = mk.x ? (_Float16)acc[mi][ni][0] : (_Float16)(-30000.0f);
            o[1] = mk.y ? (_Float16)acc[mi][ni][1] : (_Float16)(-30000.0f);
            o[2] = mk.z ? (_Float16)acc[mi][ni][2] : (_Float16)(-30000.0f);
            o[3] = mk.w ? (_Float16)acc[mi][ni][3] : (_Float16)(-30000.0f);
            *(f16x4*)(Ez + (size_t)s * Ss + t0) = o;
        }
    }
}

// ---------------------------------------------------------------------------
// softmax_pk: one block = 8 consecutive rows of one z-slice. Output k-pack8.
// Grid (NZ, 128): z in blockIdx.x -> same XCD as the energy blocks that wrote
// this z's E (L2-hit reads) and the pv blocks that will read at.
// ---------------------------------------------------------------------------
__global__ __launch_bounds__(256) void softmax_pk(
    const _Float16* __restrict__ E, _Float16* __restrict__ At)
{
    const int rb = blockIdx.x * 128 + blockIdx.y;    // global row-group
    const _Float16* e0 = E + (size_t)rb * 8 * Ss;
    const int tid = threadIdx.x;
    const int wave = tid >> 6, lane = tid & 63;
    const int t0 = tid * 4;

    float v[8][4];
#pragma unroll
    for (int r = 0; r < 8; r++) {
        f16x4 u = *(const f16x4*)(e0 + (size_t)r * Ss + t0);
#pragma unroll
        for (int j = 0; j < 4; j++) v[r][j] = (float)u[j];
    }

    __shared__ float red[4][8];
    float mx[8];
#pragma unroll
    for (int r = 0; r < 8; r++) {
        float lm = fmaxf(fmaxf(v[r][0], v[r][1]), fmaxf(v[r][2], v[r][3]));
#pragma unroll
        for (int off = 1; off < 64; off <<= 1) lm = fmaxf(lm, __shfl_xor(lm, off));
        mx[r] = lm;
    }
    if (lane == 0) {
#pragma unroll
        for (int r = 0; r < 8; r++) red[wave][r] = mx[r];
    }
    __syncthreads();
#pragma unroll
    for (int r = 0; r < 8; r++)
        mx[r] = fmaxf(fmaxf(red[0][r], red[1][r]), fmaxf(red[2][r], red[3][r]));
    __syncthreads();

    float inv[8];
#pragma unroll
    for (int r = 0; r < 8; r++) {
        v[r][0] = __expf(v[r][0] - mx[r]); v[r][1] = __expf(v[r][1] - mx[r]);
        v[r][2] = __expf(v[r][2] - mx[r]); v[r][3] = __expf(v[r][3] - mx[r]);
        float ls = (v[r][0] + v[r][1]) + (v[r][2] + v[r][3]);
#pragma unroll
        for (int off = 1; off < 64; off <<= 1) ls += __shfl_xor(ls, off);
        inv[r] = ls;
    }
    if (lane == 0) {
#pragma unroll
        for (int r = 0; r < 8; r++) red[wave][r] = inv[r];
    }
    __syncthreads();
#pragma unroll
    for (int r = 0; r < 8; r++) {
        const float s = (red[0][r] + red[1][r]) + (red[2][r] + red[3][r]);
        inv[r] = (s > 0.0f) ? (1.0f / s) : 0.0f;
    }

    _Float16* ob = At + (size_t)rb * Ss * 8;
#pragma unroll
    for (int j = 0; j < 4; j++) {
        f16x8 o;
#pragma unroll
        for (int r = 0; r < 8; r++) o[r] = (_Float16)(v[r][j] * inv[r]);
        *(f16x8*)(ob + (size_t)(t0 + j) * 8) = o;
    }
}

// ---------------------------------------------------------------------------
// pv_f16: out[t,c] = sum_s P[s,t]*v[s,c]. SWAPPED operands: A = V (M = c),
// B = at (N = t) -> each thread's 4 acc regs are consecutive c -> float4 Out
// stores + f16x4 Xp loads. Grid (NZ, 8, 4): z -> XCD (at/V read L2 hits).
// ---------------------------------------------------------------------------
__global__ __launch_bounds__(256) void pv_f16(
    const _Float16* __restrict__ At, const _Float16* __restrict__ Vpk,
    const _Float16* __restrict__ Xp, const float* __restrict__ G,
    float* __restrict__ Out, int h0, int NC)
{
    __shared__ _Float16 lsP[2][4096];   // at chunks [chunk][t]
    __shared__ _Float16 lsV[2][4096];   // V chunks [chunk][c]
    const int zl = blockIdx.x;
    const int b = zl & 1, hloc = zl >> 1;
    const int h = h0 + hloc;
    const _Float16* az = At + (size_t)zl * Ss * Ss;   // k-pack8 per z-slice

    const int t = threadIdx.x;
    const int lane = t & 63, wave = t >> 6;
    const int quad = lane >> 4, l15 = lane & 15;
    const int tb = blockIdx.y * 128;    // t-block (B / N side)
    const int cb = blockIdx.z * 128;    // c-block (A / M side)
    const int cw = (wave >> 1) * 64, tw = (wave & 1) * 64;

    const _Float16* pg = az + ((size_t)(t >> 7) * Ss + tb + (t & 127)) * 8;
    const _Float16* vg = Vpk + (((size_t)((b * Ss) >> 3) + (t >> 7)) * NC
                                + hloc * Dd + cb + (t & 127)) * 8;
    const size_t acs = (size_t)Ss * 8;
    const size_t vcs = (size_t)NC * 8;

    f32x4 acc[4][4] = {};
    GLOAD16(pg,           &lsP[0][t * 8]);
    GLOAD16(pg + 2 * acs, &lsP[0][t * 8 + 2048]);
    GLOAD16(vg,           &lsV[0][t * 8]);
    GLOAD16(vg + 2 * vcs, &lsV[0][t * 8 + 2048]);
    __syncthreads();
    int cur = 0;
    for (int kb = 0; kb < Ss; kb += 32) {
        if (kb + 32 < Ss) {
            const int nb = cur ^ 1;
            GLOAD16(pg + ((size_t)(kb >> 3) + 4) * acs, &lsP[nb][t * 8]);
            GLOAD16(pg + ((size_t)(kb >> 3) + 6) * acs, &lsP[nb][t * 8 + 2048]);
            GLOAD16(vg + ((size_t)(kb >> 3) + 4) * vcs, &lsV[nb][t * 8]);
            GLOAD16(vg + ((size_t)(kb >> 3) + 6) * vcs, &lsV[nb][t * 8 + 2048]);
        }
        f16x8 af[4], bf[4];
#pragma unroll
        for (int mi = 0; mi < 4; mi++)
            af[mi] = *(const f16x8*)&lsV[cur][quad * 1024 + (cw + mi * 16 + l15) * 8];
#pragma unroll
        for (int ni = 0; ni < 4; ni++)
            bf[ni] = *(const f16x8*)&lsP[cur][quad * 1024 + (tw + ni * 16 + l15) * 8];
#pragma unroll
        for (int mi = 0; mi < 4; mi++)
#pragma unroll
            for (int ni = 0; ni < 4; ni++)
                acc[mi][ni] = __builtin_amdgcn_mfma_f32_16x16x32_f16(af[mi], bf[ni], acc[mi][ni], 0, 0, 0);
        __syncthreads();
        cur ^= 1;
    }

    const float g = G[h];
    const float inv = 1.0f / (g + 1.0f);
#pragma unroll
    for (int mi = 0; mi < 4; mi++) {
        const int c0 = cb + cw + mi * 16 + quad * 4;
#pragma unroll
        for (int ni = 0; ni < 4; ni++) {
            const int tt = tb + tw + ni * 16 + l15;
            const f16x4 xpv = *(const f16x4*)(Xp + (size_t)(b * Ss + tt) * Dd + c0);
            float4 o;
            o.x = (g * acc[mi][ni][0] + (float)xpv[0]) * inv;
            o.y = (g * acc[mi][ni][1] + (float)xpv[1]) * inv;
            o.z = (g * acc[mi][ni][2] + (float)xpv[2]) * inv;
            o.w = (g * acc[mi][ni][3] + (float)xpv[3]) * inv;
            *(float4*)(Out + ((size_t)((b * Hh + h) * Ss + tt)) * Dd + c0) = o;
        }
    }
}

// ---------------------------------------------------------------------------
// Workspace (HG=4, guaranteed fit in 62 MiB; HG=8 if ws >= 128 MiB):
//   Wbuf  512*NC f16          (k-pack8 staging, reused per weight)
//   q, k  [2048][NC] f16 row-major
//   v     [2048][NC] f16 k-pack8 over rows
//   xp    [2048][512] f16
//   en    [2*HG][1024][1024] f16       (xf/yf staging aliases its head)
//   at    [2*HG] k-pack8 f16
// ---------------------------------------------------------------------------
extern "C" void kernel_launch(void* const* d_in, const int* in_sizes, int n_in,
                              void* d_out, int out_size, void* d_ws, size_t ws_size,
                              hipStream_t stream) {
    const float* x    = (const float*)d_in[0];
    const float* y    = (const float*)d_in[1];
    const float* Wq   = (const float*)d_in[2];
    const float* bq   = (const float*)d_in[3];
    const float* Wk   = (const float*)d_in[4];
    const float* bk   = (const float*)d_in[5];
    const float* Wv   = (const float*)d_in[6];
    const float* bv   = (const float*)d_in[7];
    const float* Wp   = (const float*)d_in[8];
    const float* gm   = (const float*)d_in[9];
    const int*   mask = (const int*)d_in[10];

    const int HG = (ws_size >= (size_t)134217728) ? 8 : 4;   // heads per group
    const int NC = HG * Dd;
    const int NZ = 2 * HG;                                    // z per group

    char* ws = (char*)d_ws;
    size_t off = 0;
    _Float16* Wbuf = (_Float16*)(ws + off); off += (size_t)512 * NC * 2;
    _Float16* qb   = (_Float16*)(ws + off); off += (size_t)Mm * NC * 2;
    _Float16* kb   = (_Float16*)(ws + off); off += (size_t)Mm * NC * 2;
    _Float16* vb   = (_Float16*)(ws + off); off += (size_t)Mm * NC * 2;
    _Float16* xp   = (_Float16*)(ws + off); off += (size_t)Mm * Dd * 2;
    _Float16* en   = (_Float16*)(ws + off); off += (size_t)NZ * Ss * Ss * 2;
    _Float16* at   = (_Float16*)(ws + off);
    _Float16* xf   = en;                      // staging inside en region
    _Float16* yf   = en + (size_t)Mm * 512;   // (4 MiB << en size)

    dim3 blk(256);
    const int NXY = Mm * 512;

    // xp = x @ Wp (no bias)
    cvt_f16<<<dim3(NXY / 1024), blk, 0, stream>>>(x, xf, NXY);
    cvt_w_pk<<<dim3(2, 64), blk, 0, stream>>>(Wp, Dd, 0, Wbuf, Dd);
    proj_f16<<<dim3(4, 16), blk, 0, stream>>>(xf, Wbuf, nullptr, 0, xp, Dd, 0);

    for (int h0 = 0; h0 < Hh; h0 += HG) {
        // re-stage x/y (en region was clobbered by previous group's energy)
        cvt_f16<<<dim3(NXY / 1024), blk, 0, stream>>>(x, xf, NXY);
        cvt_f16<<<dim3(NXY / 1024), blk, 0, stream>>>(y, yf, NXY);

        cvt_w_pk<<<dim3(NC / 256, 64), blk, 0, stream>>>(Wq, HD, h0 * Dd, Wbuf, NC);
        proj_f16<<<dim3(NC / 128, 16), blk, 0, stream>>>(xf, Wbuf, bq, h0 * Dd, qb, NC, 0);
        cvt_w_pk<<<dim3(NC / 256, 64), blk, 0, stream>>>(Wk, HD, h0 * Dd, Wbuf, NC);
        proj_f16<<<dim3(NC / 128, 16), blk, 0, stream>>>(yf, Wbuf, bk, h0 * Dd, kb, NC, 0);
        cvt_w_pk<<<dim3(NC / 256, 64), blk, 0, stream>>>(Wv, HD, h0 * Dd, Wbuf, NC);
        proj_f16<<<dim3(NC / 128, 16), blk, 0, stream>>>(yf, Wbuf, bv, h0 * Dd, vb, NC, 1);

        // z -> XCD affinity chain: energy writes E, softmax reads E / writes
        // at, pv reads at — all for z on XCD z%8.
        energy_f16<<<dim3(NZ, 8, 8), blk, 0, stream>>>(qb, kb, mask, en, NC);
        softmax_pk<<<dim3(NZ, 128), blk, 0, stream>>>(en, at);
        pv_f16<<<dim3(NZ, 8, 4), blk, 0, stream>>>(at, vb, xp, gm, (float*)d_out, h0, NC);
    }
}

// Round 3
// 235.403 us; speedup vs baseline: 1.4700x; 1.1331x over previous
//
#include <hip/hip_runtime.h>
#include <stdint.h>

// Problem constants (fp32 inputs/outputs)
#define Bb 2
#define Ss 1024
#define Dd 512
#define Hh 8
#define HD 4096   // Hh*Dd
#define Mm 2048   // Bb*Ss

typedef _Float16 f16x8 __attribute__((ext_vector_type(8)));
typedef _Float16 f16x4 __attribute__((ext_vector_type(4)));
typedef float    f32x4 __attribute__((ext_vector_type(4)));

// async global->LDS, 16B per lane. dest must be linear: base + lane*16.
#define GLOAD16(g, l)                                                          \
    __builtin_amdgcn_global_load_lds(                                          \
        (const __attribute__((address_space(1))) void*)(g),                    \
        (__attribute__((address_space(3))) void*)(l), 16, 0, 0)

// ---------------------------------------------------------------------------
// cvt_f16: fp32 -> f16 elementwise (x/y staging). n multiple of 1024.
// ---------------------------------------------------------------------------
__global__ __launch_bounds__(256) void cvt_f16(
    const float* __restrict__ in, _Float16* __restrict__ out, int n)
{
    int i = (blockIdx.x * 256 + threadIdx.x) * 4;
    if (i < n) {
        float4 u = *(const float4*)(in + i);
        f16x4 o;
        o[0] = (_Float16)u.x; o[1] = (_Float16)u.y;
        o[2] = (_Float16)u.z; o[3] = (_Float16)u.w;
        *(f16x4*)(out + i) = o;
    }
}

// ---------------------------------------------------------------------------
// cvt_w_pk: W fp32 [512][ld], cols [col0, col0+NC) -> f16 k-pack8:
//   out[((k/8)*NC + n)*8 + (k%8)]
// ---------------------------------------------------------------------------
__global__ __launch_bounds__(256) void cvt_w_pk(
    const float* __restrict__ W, int ld, int col0,
    _Float16* __restrict__ out, int NC)
{
    const int n  = blockIdx.x * 256 + threadIdx.x;
    const int k0 = blockIdx.y * 8;
    f16x8 o;
#pragma unroll
    for (int j = 0; j < 8; j++)
        o[j] = (_Float16)W[(size_t)(k0 + j) * ld + col0 + n];
    *(f16x8*)(out + ((size_t)(k0 >> 3) * NC + n) * 8) = o;
}

// fused q/k/v weight convert: blockIdx.z selects W and output slot
__global__ __launch_bounds__(256) void cvt_w_pk3(
    const float* __restrict__ Wq, const float* __restrict__ Wk,
    const float* __restrict__ Wv, int ld, int col0,
    _Float16* __restrict__ out, int NC, size_t slot)
{
    const int z = blockIdx.z;
    const float* W = (z == 0) ? Wq : (z == 1) ? Wk : Wv;
    _Float16* o0 = out + (size_t)z * slot;
    const int n  = blockIdx.x * 256 + threadIdx.x;
    const int k0 = blockIdx.y * 8;
    f16x8 o;
#pragma unroll
    for (int j = 0; j < 8; j++)
        o[j] = (_Float16)W[(size_t)(k0 + j) * ld + col0 + n];
    *(f16x8*)(o0 + ((size_t)(k0 >> 3) * NC + n) * 8) = o;
}

// ---------------------------------------------------------------------------
// proj_body: C[2048, NC] = A[2048,512](f16 row-major) @ Wpk(k-pack8) + bias.
// 128x128 tile, 4 waves, 64x64/wave, 2-phase dbuf LDS via global_load_lds.
// packC=1 stores f16x4 (pack8 rows r=0..3 contiguous halves).
// ---------------------------------------------------------------------------
__device__ __forceinline__ void proj_body(
    const _Float16* __restrict__ A, const _Float16* __restrict__ Wpk,
    const float* __restrict__ bias, int bias0,
    _Float16* __restrict__ C, int NC, int packC, int bx, int by)
{
    __shared__ _Float16 lsA[2][4096];
    __shared__ _Float16 lsB[2][4096];
    const int t = threadIdx.x;
    const int lane = t & 63, wave = t >> 6;
    const int quad = lane >> 4, l15 = lane & 15;
    const int m0b = by * 128, n0b = bx * 128;
    const int aw = (wave >> 1) * 64, bw = (wave & 1) * 64;
    const int qx = (quad ^ ((l15 >> 2) & 3)) * 8;

    const _Float16* ag = A + (size_t)(m0b + (t >> 2)) * Dd
                           + ((t & 3) ^ ((t >> 4) & 3)) * 8;
    const _Float16* bg = Wpk + ((size_t)(t >> 7) * NC + n0b + (t & 127)) * 8;
    const size_t arj = (size_t)64 * Dd;
    const size_t bcs = (size_t)NC * 8;

    f32x4 acc[4][4] = {};
    GLOAD16(ag,           &lsA[0][t * 8]);
    GLOAD16(ag + arj,     &lsA[0][t * 8 + 2048]);
    GLOAD16(bg,           &lsB[0][t * 8]);
    GLOAD16(bg + 2 * bcs, &lsB[0][t * 8 + 2048]);
    __syncthreads();
    int cur = 0;
    for (int kb = 0; kb < Dd; kb += 32) {
        if (kb + 32 < Dd) {
            const int nb = cur ^ 1;
            GLOAD16(ag + kb + 32,       &lsA[nb][t * 8]);
            GLOAD16(ag + arj + kb + 32, &lsA[nb][t * 8 + 2048]);
            GLOAD16(bg + (size_t)((kb >> 3) + 4) * bcs, &lsB[nb][t * 8]);
            GLOAD16(bg + (size_t)((kb >> 3) + 6) * bcs, &lsB[nb][t * 8 + 2048]);
        }
        f16x8 af[4], bf[4];
#pragma unroll
        for (int mi = 0; mi < 4; mi++)
            af[mi] = *(const f16x8*)&lsA[cur][(aw + mi * 16 + l15) * 32 + qx];
#pragma unroll
        for (int ni = 0; ni < 4; ni++)
            bf[ni] = *(const f16x8*)&lsB[cur][quad * 1024 + (bw + ni * 16 + l15) * 8];
#pragma unroll
        for (int mi = 0; mi < 4; mi++)
#pragma unroll
            for (int ni = 0; ni < 4; ni++)
                acc[mi][ni] = __builtin_amdgcn_mfma_f32_16x16x32_f16(af[mi], bf[ni], acc[mi][ni], 0, 0, 0);
        __syncthreads();
        cur ^= 1;
    }

#pragma unroll
    for (int mi = 0; mi < 4; mi++) {
        const int row0 = m0b + aw + mi * 16 + quad * 4;
#pragma unroll
        for (int ni = 0; ni < 4; ni++) {
            const int col = n0b + bw + ni * 16 + l15;
            const float bv = bias ? bias[bias0 + col] : 0.0f;
            if (packC) {
                f16x4 o;
#pragma unroll
                for (int r = 0; r < 4; r++) o[r] = (_Float16)(acc[mi][ni][r] + bv);
                *(f16x4*)(C + ((size_t)(row0 >> 3) * NC + col) * 8 + (row0 & 7)) = o;
            } else {
#pragma unroll
                for (int r = 0; r < 4; r++)
                    C[(size_t)(row0 + r) * NC + col] = (_Float16)(acc[mi][ni][r] + bv);
            }
        }
    }
}

__global__ __launch_bounds__(256) void proj_f16(
    const _Float16* __restrict__ A, const _Float16* __restrict__ Wpk,
    const float* __restrict__ bias, int bias0,
    _Float16* __restrict__ C, int NC, int packC)
{
    proj_body(A, Wpk, bias, bias0, C, NC, packC, blockIdx.x, blockIdx.y);
}

// fused q/k/v projection: blockIdx.z selects (A, W-slot, bias, C, packC)
__global__ __launch_bounds__(256) void proj3(
    const _Float16* __restrict__ xf, const _Float16* __restrict__ yf,
    const _Float16* __restrict__ Wpk, size_t wslot,
    const float* __restrict__ bq, const float* __restrict__ bk,
    const float* __restrict__ bv,
    _Float16* __restrict__ qb, _Float16* __restrict__ kb,
    _Float16* __restrict__ vb, int NC)
{
    const int z = blockIdx.z;
    const _Float16* A = (z == 0) ? xf : yf;
    const _Float16* W = Wpk + (size_t)z * wslot;
    const float* bias = (z == 0) ? bq : (z == 1) ? bk : bv;
    _Float16* C = (z == 0) ? qb : (z == 1) ? kb : vb;
    proj_body(A, W, bias, 0, C, NC, z == 2, blockIdx.x, blockIdx.y);
}

// ---------------------------------------------------------------------------
// energy_f16: E[s,t] = sum_c q[s,c]*k[t,c]; masked t -> -30000.
// SWAPPED operands: A = K rows (M = t), B = Q rows (N = s).
// Epilogue: masked tile staged into LDS (chunk-XOR swizzle), then stored to
// E[s][t] row-major with fully-coalesced f16x8 (16B) writes — every 128B
// line fully dirtied by one thread back-to-back (kills write amplification).
// Grid (NZ, 8, 8): z in blockIdx.x -> flat%8 = z%8 (XCD affinity).
// ---------------------------------------------------------------------------
__global__ __launch_bounds__(256) void energy_f16(
    const _Float16* __restrict__ Q, const _Float16* __restrict__ Kb,
    const int* __restrict__ mask, _Float16* __restrict__ E, int NC)
{
    __shared__ _Float16 ls[16384];   // [0..8191]=A dbuf, [8192..]=B dbuf; reused for E-tile
    const int zl = blockIdx.x;
    const int b = zl & 1, hloc = zl >> 1;
    const _Float16* qz = Q + (size_t)b * Ss * NC + hloc * Dd;
    const _Float16* kz = Kb + (size_t)b * Ss * NC + hloc * Dd;
    _Float16* Ez = E + (size_t)zl * Ss * Ss;

    const int t = threadIdx.x;
    const int lane = t & 63, wave = t >> 6;
    const int quad = lane >> 4, l15 = lane & 15;
    const int tb = blockIdx.y * 128;    // t-block (A / M side, from K)
    const int sb = blockIdx.z * 128;    // s-block (B / N side, from Q)
    const int aw = (wave >> 1) * 64, bw = (wave & 1) * 64;
    const int qx = (quad ^ ((l15 >> 2) & 3)) * 8;

    const int sc = ((t & 3) ^ ((t >> 4) & 3)) * 8;   // pre-swizzled src chunk
    const _Float16* ag = kz + (size_t)(tb + (t >> 2)) * NC + sc;
    const _Float16* bg = qz + (size_t)(sb + (t >> 2)) * NC + sc;
    const size_t rj = (size_t)64 * NC;

    f32x4 acc[4][4] = {};
    GLOAD16(ag,      &ls[t * 8]);
    GLOAD16(ag + rj, &ls[t * 8 + 2048]);
    GLOAD16(bg,      &ls[8192 + t * 8]);
    GLOAD16(bg + rj, &ls[8192 + t * 8 + 2048]);
    __syncthreads();
    int cur = 0;
    for (int kb = 0; kb < Dd; kb += 32) {
        if (kb + 32 < Dd) {
            const int nb = cur ^ 1;
            GLOAD16(ag + kb + 32,      &ls[nb * 4096 + t * 8]);
            GLOAD16(ag + rj + kb + 32, &ls[nb * 4096 + t * 8 + 2048]);
            GLOAD16(bg + kb + 32,      &ls[8192 + nb * 4096 + t * 8]);
            GLOAD16(bg + rj + kb + 32, &ls[8192 + nb * 4096 + t * 8 + 2048]);
        }
        f16x8 af[4], bf[4];
#pragma unroll
        for (int mi = 0; mi < 4; mi++)
            af[mi] = *(const f16x8*)&ls[cur * 4096 + (aw + mi * 16 + l15) * 32 + qx];
#pragma unroll
        for (int ni = 0; ni < 4; ni++)
            bf[ni] = *(const f16x8*)&ls[8192 + cur * 4096 + (bw + ni * 16 + l15) * 32 + qx];
#pragma unroll
        for (int mi = 0; mi < 4; mi++)
#pragma unroll
            for (int ni = 0; ni < 4; ni++)
                acc[mi][ni] = __builtin_amdgcn_mfma_f32_16x16x32_f16(af[mi], bf[ni], acc[mi][ni], 0, 0, 0);
        __syncthreads();
        cur ^= 1;
    }

    // ---- epilogue: masked tile -> LDS [s_local][t-chunk ^ (s&7)] ----
#pragma unroll
    for (int mi = 0; mi < 4; mi++) {
        const int tl0 = aw + mi * 16 + quad * 4;     // t_local, 4 consecutive
        const int4 mk = *(const int4*)(mask + tb + tl0);
        const int chunk = tl0 >> 3;
#pragma unroll
        for (int ni = 0; ni < 4; ni++) {
            const int sl = bw + ni * 16 + l15;       // s_local
            f16x4 o;
            o[0] = mk.x ? (_Float16)acc[mi][ni][0] : (_Float16)(-30000.0f);
            o[1] = mk.y ? (_Float16)acc[mi][ni][1] : (_Float16)(-30000.0f);
            o[2] = mk.z ? (_Float16)acc[mi][ni][2] : (_Float16)(-30000.0f);
            o[3] = mk.w ? (_Float16)acc[mi][ni][3] : (_Float16)(-30000.0f);
            *(f16x4*)&ls[sl * 128 + (chunk ^ (sl & 7)) * 8 + (tl0 & 7)] = o;
        }
    }
    __syncthreads();
    // ---- coalesced store: 2 threads/row, 8x f16x8 each ----
    {
        const int sl = t >> 1, half = t & 1;
        _Float16* erow = Ez + (size_t)(sb + sl) * Ss + tb;
#pragma unroll
        for (int j = 0; j < 8; j++) {
            const int c = half * 8 + j;
            *(f16x8*)(erow + c * 8) = *(const f16x8*)&ls[sl * 128 + ((c ^ (sl & 7))) * 8];
        }
    }
}

// ---------------------------------------------------------------------------
// softmax_pk: one block = 8 consecutive rows of one z-slice. Output k-pack8.
// Grid (NZ, 128): z in blockIdx.x (XCD affinity with energy/pv).
// ---------------------------------------------------------------------------
__global__ __launch_bounds__(256) void softmax_pk(
    const _Float16* __restrict__ E, _Float16* __restrict__ At)
{
    const int rb = blockIdx.x * 128 + blockIdx.y;    // global row-group
    const _Float16* e0 = E + (size_t)rb * 8 * Ss;
    const int tid = threadIdx.x;
    const int wave = tid >> 6, lane = tid & 63;
    const int t0 = tid * 4;

    float v[8][4];
#pragma unroll
    for (int r = 0; r < 8; r++) {
        f16x4 u = *(const f16x4*)(e0 + (size_t)r * Ss + t0);
#pragma unroll
        for (int j = 0; j < 4; j++) v[r][j] = (float)u[j];
    }

    __shared__ float red[4][8];
    float mx[8];
#pragma unroll
    for (int r = 0; r < 8; r++) {
        float lm = fmaxf(fmaxf(v[r][0], v[r][1]), fmaxf(v[r][2], v[r][3]));
#pragma unroll
        for (int off = 1; off < 64; off <<= 1) lm = fmaxf(lm, __shfl_xor(lm, off));
        mx[r] = lm;
    }
    if (lane == 0) {
#pragma unroll
        for (int r = 0; r < 8; r++) red[wave][r] = mx[r];
    }
    __syncthreads();
#pragma unroll
    for (int r = 0; r < 8; r++)
        mx[r] = fmaxf(fmaxf(red[0][r], red[1][r]), fmaxf(red[2][r], red[3][r]));
    __syncthreads();

    float inv[8];
#pragma unroll
    for (int r = 0; r < 8; r++) {
        v[r][0] = __expf(v[r][0] - mx[r]); v[r][1] = __expf(v[r][1] - mx[r]);
        v[r][2] = __expf(v[r][2] - mx[r]); v[r][3] = __expf(v[r][3] - mx[r]);
        float ls = (v[r][0] + v[r][1]) + (v[r][2] + v[r][3]);
#pragma unroll
        for (int off = 1; off < 64; off <<= 1) ls += __shfl_xor(ls, off);
        inv[r] = ls;
    }
    if (lane == 0) {
#pragma unroll
        for (int r = 0; r < 8; r++) red[wave][r] = inv[r];
    }
    __syncthreads();
#pragma unroll
    for (int r = 0; r < 8; r++) {
        const float s = (red[0][r] + red[1][r]) + (red[2][r] + red[3][r]);
        inv[r] = (s > 0.0f) ? (1.0f / s) : 0.0f;
    }

    _Float16* ob = At + (size_t)rb * Ss * 8;
#pragma unroll
    for (int j = 0; j < 4; j++) {
        f16x8 o;
#pragma unroll
        for (int r = 0; r < 8; r++) o[r] = (_Float16)(v[r][j] * inv[r]);
        *(f16x8*)(ob + (size_t)(t0 + j) * 8) = o;
    }
}

// ---------------------------------------------------------------------------
// pv_f16: out[t,c] = sum_s P[s,t]*v[s,c]. M = t (from at), N = c (from V):
// scalar f32 Out stores are 64B-contiguous per quad, lines fully dirtied.
// Grid (NZ, 8, 4): z -> XCD (at/V reads hit local L2).
// ---------------------------------------------------------------------------
__global__ __launch_bounds__(256) void pv_f16(
    const _Float16* __restrict__ At, const _Float16* __restrict__ Vpk,
    const _Float16* __restrict__ Xp, const float* __restrict__ G,
    float* __restrict__ Out, int h0, int NC)
{
    __shared__ _Float16 lsP[2][4096];   // at chunks [s-chunk][t]
    __shared__ _Float16 lsV[2][4096];   // V chunks [s-chunk][c]
    const int zl = blockIdx.x;
    const int b = zl & 1, hloc = zl >> 1;
    const int h = h0 + hloc;
    const _Float16* az = At + (size_t)zl * Ss * Ss;   // k-pack8 per z-slice

    const int t = threadIdx.x;
    const int lane = t & 63, wave = t >> 6;
    const int quad = lane >> 4, l15 = lane & 15;
    const int tb = blockIdx.y * 128;    // t-block (A / M side)
    const int cb = blockIdx.z * 128;    // c-block (B / N side)
    const int tw = (wave >> 1) * 64, cw = (wave & 1) * 64;

    const _Float16* pg = az + ((size_t)(t >> 7) * Ss + tb + (t & 127)) * 8;
    const _Float16* vg = Vpk + (((size_t)((b * Ss) >> 3) + (t >> 7)) * NC
                                + hloc * Dd + cb + (t & 127)) * 8;
    const size_t acs = (size_t)Ss * 8;
    const size_t vcs = (size_t)NC * 8;

    f32x4 acc[4][4] = {};
    GLOAD16(pg,           &lsP[0][t * 8]);
    GLOAD16(pg + 2 * acs, &lsP[0][t * 8 + 2048]);
    GLOAD16(vg,           &lsV[0][t * 8]);
    GLOAD16(vg + 2 * vcs, &lsV[0][t * 8 + 2048]);
    __syncthreads();
    int cur = 0;
    for (int kb = 0; kb < Ss; kb += 32) {
        if (kb + 32 < Ss) {
            const int nb = cur ^ 1;
            GLOAD16(pg + ((size_t)(kb >> 3) + 4) * acs, &lsP[nb][t * 8]);
            GLOAD16(pg + ((size_t)(kb >> 3) + 6) * acs, &lsP[nb][t * 8 + 2048]);
            GLOAD16(vg + ((size_t)(kb >> 3) + 4) * vcs, &lsV[nb][t * 8]);
            GLOAD16(vg + ((size_t)(kb >> 3) + 6) * vcs, &lsV[nb][t * 8 + 2048]);
        }
        f16x8 af[4], bf[4];
#pragma unroll
        for (int mi = 0; mi < 4; mi++)
            af[mi] = *(const f16x8*)&lsP[cur][quad * 1024 + (tw + mi * 16 + l15) * 8];
#pragma unroll
        for (int ni = 0; ni < 4; ni++)
            bf[ni] = *(const f16x8*)&lsV[cur][quad * 1024 + (cw + ni * 16 + l15) * 8];
#pragma unroll
        for (int mi = 0; mi < 4; mi++)
#pragma unroll
            for (int ni = 0; ni < 4; ni++)
                acc[mi][ni] = __builtin_amdgcn_mfma_f32_16x16x32_f16(af[mi], bf[ni], acc[mi][ni], 0, 0, 0);
        __syncthreads();
        cur ^= 1;
    }

    const float g = G[h];
    const float inv = 1.0f / (g + 1.0f);
#pragma unroll
    for (int mi = 0; mi < 4; mi++) {
        const int tr0 = tb + tw + mi * 16 + quad * 4;
#pragma unroll
        for (int r = 0; r < 4; r++) {
            const int tt = tr0 + r;
            const _Float16* xrow = Xp + (size_t)(b * Ss + tt) * Dd;
            float* orow = Out + ((size_t)((b * Hh + h) * Ss + tt)) * Dd;
#pragma unroll
            for (int ni = 0; ni < 4; ni++) {
                const int c = cb + cw + ni * 16 + l15;
                orow[c] = (g * acc[mi][ni][r] + (float)xrow[c]) * inv;
            }
        }
    }
}

// ---------------------------------------------------------------------------
// Workspace:
//   Wbuf  (HG==8 ? 3 : 1) slots of 512*NC f16 (k-pack8 weights)
//   q, k  [2048][NC] f16 row-major
//   v     [2048][NC] f16 k-pack8 over rows
//   xp    [2048][512] f16
//   en    [NZ][1024][1024] f16      (xf/yf staging aliases its head)
//   at    [NZ] k-pack8 f16
// HG=4 total ~60 MiB (fits 62 MiB floor); HG=8 total ~126 MiB (needs >=128MiB)
// ---------------------------------------------------------------------------
extern "C" void kernel_launch(void* const* d_in, const int* in_sizes, int n_in,
                              void* d_out, int out_size, void* d_ws, size_t ws_size,
                              hipStream_t stream) {
    const float* x    = (const float*)d_in[0];
    const float* y    = (const float*)d_in[1];
    const float* Wq   = (const float*)d_in[2];
    const float* bq   = (const float*)d_in[3];
    const float* Wk   = (const float*)d_in[4];
    const float* bk   = (const float*)d_in[5];
    const float* Wv   = (const float*)d_in[6];
    const float* bv   = (const float*)d_in[7];
    const float* Wp   = (const float*)d_in[8];
    const float* gm   = (const float*)d_in[9];
    const int*   mask = (const int*)d_in[10];

    const int HG = (ws_size >= (size_t)134217728) ? 8 : 4;   // heads per group
    const int NC = HG * Dd;
    const int NZ = 2 * HG;                                    // z per group
    const size_t wslot = (size_t)512 * NC;                    // f16 per W slot

    char* ws = (char*)d_ws;
    size_t off = 0;
    _Float16* Wbuf = (_Float16*)(ws + off); off += (size_t)(HG == 8 ? 3 : 1) * wslot * 2;
    _Float16* qb   = (_Float16*)(ws + off); off += (size_t)Mm * NC * 2;
    _Float16* kb   = (_Float16*)(ws + off); off += (size_t)Mm * NC * 2;
    _Float16* vb   = (_Float16*)(ws + off); off += (size_t)Mm * NC * 2;
    _Float16* xp   = (_Float16*)(ws + off); off += (size_t)Mm * Dd * 2;
    _Float16* en   = (_Float16*)(ws + off); off += (size_t)NZ * Ss * Ss * 2;
    _Float16* at   = (_Float16*)(ws + off);
    _Float16* xf   = en;                      // staging inside en region
    _Float16* yf   = en + (size_t)Mm * 512;

    dim3 blk(256);
    const int NXY = Mm * 512;

    if (HG == 8) {
        // single group covering all heads (h0 = 0)
        cvt_f16<<<dim3(NXY / 1024), blk, 0, stream>>>(x, xf, NXY);
        cvt_f16<<<dim3(NXY / 1024), blk, 0, stream>>>(y, yf, NXY);

        // xp = x @ Wp (no bias) — uses Wbuf slot 0 before qkv convert
        cvt_w_pk<<<dim3(2, 64), blk, 0, stream>>>(Wp, Dd, 0, Wbuf, Dd);
        proj_f16<<<dim3(4, 16), blk, 0, stream>>>(xf, Wbuf, nullptr, 0, xp, Dd, 0);

        cvt_w_pk3<<<dim3(NC / 256, 64, 3), blk, 0, stream>>>(Wq, Wk, Wv, HD, 0, Wbuf, NC, wslot);
        proj3<<<dim3(NC / 128, 16, 3), blk, 0, stream>>>(xf, yf, Wbuf, wslot,
                                                         bq, bk, bv, qb, kb, vb, NC);

        energy_f16<<<dim3(NZ, 8, 8), blk, 0, stream>>>(qb, kb, mask, en, NC);
        softmax_pk<<<dim3(NZ, 128), blk, 0, stream>>>(en, at);
        pv_f16<<<dim3(NZ, 8, 4), blk, 0, stream>>>(at, vb, xp, gm, (float*)d_out, 0, NC);
    } else {
        // xp = x @ Wp (no bias)
        cvt_f16<<<dim3(NXY / 1024), blk, 0, stream>>>(x, xf, NXY);
        cvt_w_pk<<<dim3(2, 64), blk, 0, stream>>>(Wp, Dd, 0, Wbuf, Dd);
        proj_f16<<<dim3(4, 16), blk, 0, stream>>>(xf, Wbuf, nullptr, 0, xp, Dd, 0);

        for (int h0 = 0; h0 < Hh; h0 += HG) {
            // re-stage x/y (en region clobbered by previous group's energy)
            cvt_f16<<<dim3(NXY / 1024), blk, 0, stream>>>(x, xf, NXY);
            cvt_f16<<<dim3(NXY / 1024), blk, 0, stream>>>(y, yf, NXY);

            cvt_w_pk<<<dim3(NC / 256, 64), blk, 0, stream>>>(Wq, HD, h0 * Dd, Wbuf, NC);
            proj_f16<<<dim3(NC / 128, 16), blk, 0, stream>>>(xf, Wbuf, bq, h0 * Dd, qb, NC, 0);
            cvt_w_pk<<<dim3(NC / 256, 64), blk, 0, stream>>>(Wk, HD, h0 * Dd, Wbuf, NC);
            proj_f16<<<dim3(NC / 128, 16), blk, 0, stream>>>(yf, Wbuf, bk, h0 * Dd, kb, NC, 0);
            cvt_w_pk<<<dim3(NC / 256, 64), blk, 0, stream>>>(Wv, HD, h0 * Dd, Wbuf, NC);
            proj_f16<<<dim3(NC / 128, 16), blk, 0, stream>>>(yf, Wbuf, bv, h0 * Dd, vb, NC, 1);

            energy_f16<<<dim3(NZ, 8, 8), blk, 0, stream>>>(qb, kb, mask, en, NC);
            softmax_pk<<<dim3(NZ, 128), blk, 0, stream>>>(en, at);
            pv_f16<<<dim3(NZ, 8, 4), blk, 0, stream>>>(at, vb, xp, gm, (float*)d_out, h0, NC);
        }
    }
}